// Round 7
// baseline (2939.714 us; speedup 1.0000x reference)
//
#include <hip/hip_runtime.h>
#include <hip/hip_bf16.h>
#include <math.h>

namespace {

constexpr int Bc  = 8;
constexpr int Lc  = 2048;
constexpr int VOC = 1969;
constexpr int VOCP = 2048;            // padded vocab rows for logits GEMM
constexpr int DM  = 768;
constexpr int DI  = 1536;
constexpr int DS  = 16;
constexpr int DC  = 4;
constexpr int DR  = 48;
constexpr int M   = Bc * Lc;          // 16384 rows
constexpr int NC  = 32;               // scan chunks
constexpr int CT  = Lc / NC;          // 64 timesteps per chunk
constexpr float EPS_ = 1e-5f;

typedef __bf16 bf16x8 __attribute__((ext_vector_type(8)));
typedef float  f32x4  __attribute__((ext_vector_type(4)));

__device__ __forceinline__ float siluf(float x) { return x / (1.f + __expf(-x)); }
__device__ __forceinline__ float softplusf(float x) {
  return (x > 20.f) ? x : __logf(1.f + __expf(x));
}

#define GLOAD16(gp, lp)                                                        \
  __builtin_amdgcn_global_load_lds(                                            \
      (const __attribute__((address_space(1))) void*)(gp),                     \
      (__attribute__((address_space(3))) void*)(lp), 16, 0, 0)

// -------- f32 -> bf16 conversion (packed) --------
__global__ __launch_bounds__(256) void k_f2b(const float* __restrict__ in,
                                             __bf16* __restrict__ out, int n4) {
  for (int i = blockIdx.x * 256 + threadIdx.x; i < n4; i += gridDim.x * 256) {
    float4 v = *(const float4*)(in + (size_t)i * 4);
    __bf16* o = out + (size_t)i * 4;
    o[0] = (__bf16)v.x; o[1] = (__bf16)v.y; o[2] = (__bf16)v.z; o[3] = (__bf16)v.w;
  }
}

// f32 -> bf16 with per-layer row/col zero-padding.
__global__ __launch_bounds__(256) void k_f2b_pad(const float* __restrict__ in,
                                                 __bf16* __restrict__ out,
                                                 int layers, int rin, int rout,
                                                 int cin, int cout) {
  size_t total = (size_t)layers * rout * cout;
  for (size_t i = (size_t)blockIdx.x * 256 + threadIdx.x; i < total;
       i += (size_t)gridDim.x * 256) {
    int lay = (int)(i / ((size_t)rout * cout));
    int rem = (int)(i % ((size_t)rout * cout));
    int r = rem / cout, c = rem % cout;
    float v = (r < rin && c < cin) ? in[((size_t)lay * rin + r) * cin + c] : 0.f;
    out[i] = (__bf16)v;
  }
}

// h[row,d] = embed[ids[row]][d] + times[row]*time_w[d] + time_b[d]
__global__ void k_embed(const int* __restrict__ ids, const float* __restrict__ times,
                        const float* __restrict__ emb, const float* __restrict__ tw,
                        const float* __restrict__ tb, float* __restrict__ h) {
  int row = blockIdx.x;
  int id  = ids[row];
  float tv = times[row];
  const float* e = emb + (size_t)id * DM;
  for (int d = threadIdx.x; d < DM; d += blockDim.x)
    h[(size_t)row * DM + d] = e[d] + tv * tw[d] + tb[d];
}

// bf16 out: o[row,:] = x[row,:] * rsqrt(mean(x^2)+eps) * w
__global__ __launch_bounds__(256) void k_rmsnorm(const float* __restrict__ x,
                                                 const float* __restrict__ w,
                                                 __bf16* __restrict__ o) {
  int row = blockIdx.x;
  const float* xr = x + (size_t)row * DM;
  float v[3];
  float s = 0.f;
#pragma unroll
  for (int i = 0; i < 3; i++) { v[i] = xr[threadIdx.x + 256 * i]; s += v[i] * v[i]; }
#pragma unroll
  for (int off = 32; off > 0; off >>= 1) s += __shfl_down(s, off);
  __shared__ float red[4];
  int lane = threadIdx.x & 63, wv = threadIdx.x >> 6;
  if (lane == 0) red[wv] = s;
  __syncthreads();
  if (threadIdx.x == 0)
    red[0] = rsqrtf((red[0] + red[1] + red[2] + red[3]) / (float)DM + EPS_);
  __syncthreads();
  float sc = red[0];
#pragma unroll
  for (int i = 0; i < 3; i++) {
    int d = threadIdx.x + 256 * i;
    o[(size_t)row * DM + d] = (__bf16)(v[i] * sc * w[d]);
  }
}

// Depthwise causal conv (width 4) + bias + silu ; bf16x8 vectorized.
__global__ __launch_bounds__(256) void k_conv8(const __bf16* __restrict__ xb,
                                               const float* __restrict__ cwt,
                                               const float* __restrict__ cbv,
                                               __bf16* __restrict__ xo) {
  size_t idx = (size_t)blockIdx.x * 256 + threadIdx.x;   // < M*DI/8
  int dg = (int)(idx % (DI / 8));
  size_t row = idx / (DI / 8);
  int d0 = dg * 8;
  int t = (int)(row % Lc);
  size_t b = row / Lc;
  float acc[8];
  float4 cwv[8];
#pragma unroll
  for (int j = 0; j < 8; j++) {
    acc[j] = cbv[d0 + j];
    cwv[j] = *(const float4*)(cwt + (d0 + j) * DC);
  }
#pragma unroll
  for (int tap = 0; tap < DC; tap++) {
    int tt = t - (DC - 1) + tap;
    if (tt >= 0) {
      bf16x8 v = *(const bf16x8*)(xb + ((size_t)b * Lc + tt) * DI + d0);
#pragma unroll
      for (int j = 0; j < 8; j++) {
        float wt = (tap == 0) ? cwv[j].x : (tap == 1) ? cwv[j].y
                   : (tap == 2) ? cwv[j].z : cwv[j].w;
        acc[j] += wt * (float)v[j];
      }
    }
  }
  bf16x8 o;
#pragma unroll
  for (int j = 0; j < 8; j++) o[j] = (__bf16)siluf(acc[j]);
  *(bf16x8*)(xo + idx * 8) = o;
}

// ======== big-GEMM: 256x128 tile, BK=64, 8 waves, 3-buffer counted-vmcnt pipeline =======
// C[M x N] (+)= act(A[M x K] W[N x K]^T + bias).  M%256==0, N%128==0, K%64==0, K/64 >= 2.
// LDS per buffer: A 256x64 (32KB, 128B rows) + B 128x64 (16KB). 3 buffers = 144KB.
// Swizzle (rule 21, both-sides): slot' = (slot + row) & 7 within each 128B row;
// gload_lds dest is LINEAR (wave-uniform base + lane*16), global source pre-permuted
// with s = (slot' - row) & 7; ds_read applies the same rotation -> 2-way (free) reads.
// Pipeline: issue tile t+2 each iter; s_waitcnt vmcnt(12) (= 6 loads/thread x 2 tiles
// still allowed in flight) guarantees tile t landed; barrier; compute. Tail: 12->6->0.
__global__ __launch_bounds__(512, 2) void k_gemm_big(
    const __bf16* __restrict__ A, int lda,
    const __bf16* __restrict__ W, int ldw,
    const float* __restrict__ bias,
    float* __restrict__ Cf, __bf16* __restrict__ Cb, int ldc,
    int N, int K, int act, int resAdd) {
  constexpr int BUFE = 24576;             // elements per buffer (A 16384 + B 8192)
  __shared__ __bf16 lds[3 * BUFE];
  int tid = threadIdx.x;
  int l = tid & 63, w = tid >> 6;
  int wr = w >> 1, wc = w & 1;            // 4 M-waves x 2 N-waves
  int bm = blockIdx.x << 8, bn = blockIdx.y << 7;

  // --- staging: chunk c = tid + 512*i ; row = w*8 + 64*i + (l>>3), slot' = l&7 ---
  const char* gA[4];
  const char* gB[2];
#pragma unroll
  for (int i = 0; i < 4; i++) {
    int row = w * 8 + 64 * i + (l >> 3);
    int s = ((l & 7) - row) & 7;          // pre-permuted global k-slot
    gA[i] = (const char*)(A + (size_t)(bm + row) * lda) + s * 16;
  }
#pragma unroll
  for (int i = 0; i < 2; i++) {
    int row = w * 8 + 64 * i + (l >> 3);
    int s = ((l & 7) - row) & 7;
    gB[i] = (const char*)(W + (size_t)(bn + row) * ldw) + s * 16;
  }

  // --- fragment read offsets (elements), constant across K ---
  int aoff[4][2], boff[4][2];
#pragma unroll
  for (int mi = 0; mi < 4; mi++)
#pragma unroll
    for (int kk = 0; kk < 2; kk++) {
      int row = wr * 64 + mi * 16 + (l & 15);
      int sp = ((kk * 4 + (l >> 4)) + row) & 7;
      aoff[mi][kk] = row * 64 + sp * 8;
    }
#pragma unroll
  for (int ni = 0; ni < 4; ni++)
#pragma unroll
    for (int kk = 0; kk < 2; kk++) {
      int row = wc * 64 + ni * 16 + (l & 15);
      int sp = ((kk * 4 + (l >> 4)) + row) & 7;
      boff[ni][kk] = 16384 + row * 64 + sp * 8;
    }

  f32x4 acc[4][4];
#pragma unroll
  for (int i = 0; i < 4; i++)
#pragma unroll
    for (int j = 0; j < 4; j++)
#pragma unroll
      for (int e = 0; e < 4; e++) acc[i][j][e] = 0.f;

#define ISSUE_TILE(t, buf)                                                     \
  do {                                                                         \
    __bf16* Lb_ = lds + (buf) * BUFE;                                          \
    size_t kb_ = (size_t)(t) * 128;                                            \
    _Pragma("unroll")                                                          \
    for (int i_ = 0; i_ < 4; i_++)                                             \
      GLOAD16(gA[i_] + kb_, Lb_ + ((size_t)w * 64 + 512 * i_) * 8);            \
    _Pragma("unroll")                                                          \
    for (int i_ = 0; i_ < 2; i_++)                                             \
      GLOAD16(gB[i_] + kb_, Lb_ + 16384 + ((size_t)w * 64 + 512 * i_) * 8);    \
  } while (0)

  int NT = K >> 6;
  ISSUE_TILE(0, 0);
  ISSUE_TILE(1, 1);

  for (int t = 0; t < NT; ++t) {
    __builtin_amdgcn_s_barrier();             // buffer (t+2)%3's readers are done
    __builtin_amdgcn_sched_barrier(0);
    if (t + 2 < NT) {
      int bi = (t + 2) % 3;
      ISSUE_TILE(t + 2, bi);
    }
    int rem = NT - t;
    if (rem >= 3)      asm volatile("s_waitcnt vmcnt(12)" ::: "memory");
    else if (rem == 2) asm volatile("s_waitcnt vmcnt(6)" ::: "memory");
    else               asm volatile("s_waitcnt vmcnt(0)" ::: "memory");
    __builtin_amdgcn_s_barrier();             // everyone's tile-t loads landed
    __builtin_amdgcn_sched_barrier(0);

    const __bf16* Lb = lds + (t % 3) * BUFE;
    bf16x8 af[4][2], bfv[4][2];
#pragma unroll
    for (int mi = 0; mi < 4; mi++)
#pragma unroll
      for (int kk = 0; kk < 2; kk++)
        af[mi][kk] = *(const bf16x8*)(Lb + aoff[mi][kk]);
#pragma unroll
    for (int ni = 0; ni < 4; ni++)
#pragma unroll
      for (int kk = 0; kk < 2; kk++)
        bfv[ni][kk] = *(const bf16x8*)(Lb + boff[ni][kk]);
    __builtin_amdgcn_s_setprio(1);
#pragma unroll
    for (int mi = 0; mi < 4; mi++)
#pragma unroll
      for (int ni = 0; ni < 4; ni++) {
        acc[mi][ni] = __builtin_amdgcn_mfma_f32_16x16x32_bf16(
            af[mi][0], bfv[ni][0], acc[mi][ni], 0, 0, 0);
        acc[mi][ni] = __builtin_amdgcn_mfma_f32_16x16x32_bf16(
            af[mi][1], bfv[ni][1], acc[mi][ni], 0, 0, 0);
      }
    __builtin_amdgcn_s_setprio(0);
  }
#undef ISSUE_TILE

#pragma unroll
  for (int mi = 0; mi < 4; mi++) {
#pragma unroll
    for (int r = 0; r < 4; r++) {
      int grow = bm + wr * 64 + mi * 16 + (l >> 4) * 4 + r;
#pragma unroll
      for (int ni = 0; ni < 4; ni++) {
        int gcol = bn + wc * 64 + ni * 16 + (l & 15);
        if (gcol < N) {
          float v = acc[mi][ni][r];
          if (bias) v += bias[gcol];
          if (act == 1) v = softplusf(v);
          size_t off = (size_t)grow * ldc + gcol;
          if (Cb) Cb[off] = (__bf16)v;
          else if (resAdd) Cf[off] += v;
          else Cf[off] = v;
        }
      }
    }
  }
}

// ---------------- small-shape bf16 MFMA GEMM (m97 structure, 128x128, BK=32) ----------------
__global__ __launch_bounds__(256) void k_gemm_mfma(
    const __bf16* __restrict__ A, int lda,
    const __bf16* __restrict__ W, int ldw,
    const float* __restrict__ bias,
    float* __restrict__ Cf, __bf16* __restrict__ Cb, int ldc,
    int N, int K, int act, int resAdd) {
  __shared__ __bf16 As[128 * 32];
  __shared__ __bf16 Bs[128 * 32];
  int tid = threadIdx.x;
  int l = tid & 63, w = tid >> 6;
  int wr = w >> 1, wc = w & 1;
  int bm = blockIdx.x << 7, bn = blockIdx.y << 7;

  int lrow = l >> 2, lslot = l & 3;
  int r0 = w * 32 + lrow;
  int r1 = r0 + 16;
  int sg0 = (lslot - r0 - (r0 >> 2)) & 3;
  int sg1 = (lslot - r1 - (r1 >> 2)) & 3;
  const char* gA0 = (const char*)(A + (size_t)(bm + r0) * lda) + sg0 * 16;
  const char* gA1 = (const char*)(A + (size_t)(bm + r1) * lda) + sg1 * 16;
  const char* gB0 = (const char*)(W + (size_t)(bn + r0) * ldw) + sg0 * 16;
  const char* gB1 = (const char*)(W + (size_t)(bn + r1) * ldw) + sg1 * 16;
  __bf16* lA0 = As + (w * 32) * 32;
  __bf16* lA1 = As + (w * 32 + 16) * 32;
  __bf16* lB0 = Bs + (w * 32) * 32;
  __bf16* lB1 = Bs + (w * 32 + 16) * 32;

  int aoff[4], boff[4];
#pragma unroll
  for (int i = 0; i < 4; i++) {
    int ra = wr * 64 + i * 16 + (l & 15);
    aoff[i] = ra * 32 + ((((l >> 4) + ra + (ra >> 2)) & 3) << 3);
    int rb = wc * 64 + i * 16 + (l & 15);
    boff[i] = rb * 32 + ((((l >> 4) + rb + (rb >> 2)) & 3) << 3);
  }

  f32x4 acc[4][4];
#pragma unroll
  for (int i = 0; i < 4; i++)
#pragma unroll
    for (int j = 0; j < 4; j++)
#pragma unroll
      for (int e = 0; e < 4; e++) acc[i][j][e] = 0.f;

  for (int k0 = 0; k0 < K; k0 += 32) {
    size_t kb = (size_t)k0 * 2;
    __syncthreads();
    GLOAD16(gA0 + kb, lA0);
    GLOAD16(gA1 + kb, lA1);
    GLOAD16(gB0 + kb, lB0);
    GLOAD16(gB1 + kb, lB1);
    __syncthreads();
    bf16x8 af[4], bfr[4];
#pragma unroll
    for (int i = 0; i < 4; i++) {
      af[i]  = *(const bf16x8*)(As + aoff[i]);
      bfr[i] = *(const bf16x8*)(Bs + boff[i]);
    }
#pragma unroll
    for (int i = 0; i < 4; i++)
#pragma unroll
      for (int j = 0; j < 4; j++)
        acc[i][j] = __builtin_amdgcn_mfma_f32_16x16x32_bf16(af[i], bfr[j], acc[i][j], 0, 0, 0);
  }

#pragma unroll
  for (int i = 0; i < 4; i++) {
#pragma unroll
    for (int r = 0; r < 4; r++) {
      int grow = bm + wr * 64 + i * 16 + (l >> 4) * 4 + r;
#pragma unroll
      for (int j = 0; j < 4; j++) {
        int gcol = bn + wc * 64 + j * 16 + (l & 15);
        if (gcol < N) {
          float v = acc[i][j][r];
          if (bias) v += bias[gcol];
          if (act == 1) v = softplusf(v);
          size_t off = (size_t)grow * ldc + gcol;
          if (Cb) Cb[off] = (__bf16)v;
          else if (resAdd) Cf[off] += v;
          else Cf[off] = v;
        }
      }
    }
  }
}

// ---------------- chunked selective scan ----------------
__global__ __launch_bounds__(256) void k_scan1(
    const __bf16* __restrict__ dlt,
    const __bf16* __restrict__ u_xc,
    const __bf16* __restrict__ xdbl,
    const float* __restrict__ alog,
    float* __restrict__ sc) {
  __shared__ float bcs[CT][32];
  int b = blockIdx.z, c = blockIdx.y;
  int d = blockIdx.x * 256 + threadIdx.x;
  int row0 = b * Lc + c * CT;
#pragma unroll
  for (int k = 0; k < (CT * 32) / 256; k++) {
    int i = k * 256 + threadIdx.x;
    int t = i >> 5, j = i & 31;
    bcs[t][j] = (float)xdbl[(size_t)(row0 + t) * 80 + 48 + j];
  }
  float Av[16];
#pragma unroll
  for (int n = 0; n < 16; n++) Av[n] = -__expf(alog[d * DS + n]);
  float h[16], P[16];
#pragma unroll
  for (int n = 0; n < 16; n++) { h[n] = 0.f; P[n] = 1.f; }
  __syncthreads();
  for (int t = 0; t < CT; t++) {
    size_t row = row0 + t;
    float dl = (float)dlt[row * DI + d];
    float u  = (float)u_xc[row * DI + d];
    float du = dl * u;
#pragma unroll
    for (int n = 0; n < 16; n++) {
      float e = __expf(dl * Av[n]);
      h[n] = h[n] * e + du * bcs[t][n];
      P[n] *= e;
    }
  }
  float* o = sc + (((size_t)b * NC + c) * DI + d) * 32;
#pragma unroll
  for (int n = 0; n < 16; n += 4) {
    *(float4*)(o + n)      = make_float4(h[n], h[n + 1], h[n + 2], h[n + 3]);
    *(float4*)(o + 16 + n) = make_float4(P[n], P[n + 1], P[n + 2], P[n + 3]);
  }
}

__global__ __launch_bounds__(256) void k_scan2(float* __restrict__ sc) {
  int g = blockIdx.x * 256 + threadIdx.x;
  int n = g & 15;
  int rest = g >> 4;
  int d = rest % DI;
  int b = rest / DI;
  float cur = 0.f;
  for (int c = 0; c < NC; c++) {
    float* p = sc + (((size_t)b * NC + c) * DI + d) * 32;
    float hf = p[n];
    float pd = p[16 + n];
    p[n] = cur;
    cur = pd * cur + hf;
  }
}

__global__ __launch_bounds__(256) void k_scan3(
    const __bf16* __restrict__ dlt,
    const __bf16* __restrict__ zb,
    __bf16* __restrict__ u_xc,          // in: u, out: y*silu(z)
    const __bf16* __restrict__ xdbl,
    const float* __restrict__ alog,
    const float* __restrict__ dsk,
    const float* __restrict__ sc) {
  __shared__ float bcs[CT][32];
  int b = blockIdx.z, c = blockIdx.y;
  int d = blockIdx.x * 256 + threadIdx.x;
  int row0 = b * Lc + c * CT;
#pragma unroll
  for (int k = 0; k < (CT * 32) / 256; k++) {
    int i = k * 256 + threadIdx.x;
    int t = i >> 5, j = i & 31;
    bcs[t][j] = (float)xdbl[(size_t)(row0 + t) * 80 + 48 + j];
  }
  float Av[16];
#pragma unroll
  for (int n = 0; n < 16; n++) Av[n] = -__expf(alog[d * DS + n]);
  float Dv = dsk[d];
  float h[16];
  const float* ip = sc + (((size_t)b * NC + c) * DI + d) * 32;
#pragma unroll
  for (int n = 0; n < 16; n += 4) {
    float4 v = *(const float4*)(ip + n);
    h[n] = v.x; h[n + 1] = v.y; h[n + 2] = v.z; h[n + 3] = v.w;
  }
  __syncthreads();
  for (int t = 0; t < CT; t++) {
    size_t row = row0 + t;
    float dl = (float)dlt[row * DI + d];
    float u  = (float)u_xc[row * DI + d];
    float du = dl * u;
    float y = 0.f;
#pragma unroll
    for (int n = 0; n < 16; n++) {
      float e = __expf(dl * Av[n]);
      h[n] = h[n] * e + du * bcs[t][n];
      y += h[n] * bcs[t][16 + n];
    }
    y += u * Dv;
    float z = (float)zb[row * DI + d];
    u_xc[row * DI + d] = (__bf16)(y * siluf(z));
  }
}

}  // namespace

extern "C" void kernel_launch(void* const* d_in, const int* in_sizes, int n_in,
                              void* d_out, int out_size, void* d_ws, size_t ws_size,
                              hipStream_t stream) {
  const int*   ids   = (const int*)d_in[0];
  const float* times = (const float*)d_in[1];
  const float* emb   = (const float*)d_in[3];
  const float* tw    = (const float*)d_in[4];
  const float* tb    = (const float*)d_in[5];
  const float* inw   = (const float*)d_in[6];
  const float* cw    = (const float*)d_in[7];
  const float* cb    = (const float*)d_in[8];
  const float* xw    = (const float*)d_in[9];
  const float* dtw   = (const float*)d_in[10];
  const float* dtb   = (const float*)d_in[11];
  const float* alog  = (const float*)d_in[12];
  const float* dsk   = (const float*)d_in[13];
  const float* ow    = (const float*)d_in[14];
  const float* nw    = (const float*)d_in[15];
  const float* nfw   = (const float*)d_in[16];
  float* out = (float*)d_out;

  // ---- workspace layout (f32 first, then bf16; all 16B aligned) ----
  float* wsf  = (float*)d_ws;
  float* h    = wsf;  wsf += (size_t)M * DM;                 // 50.3 MB
  float* scb  = wsf;  wsf += (size_t)Bc * NC * DI * 32;      // 50.3 MB
  __bf16* wsb = (__bf16*)wsf;
  __bf16* hnb   = wsb;  wsb += (size_t)M * DM;               // 25.2 MB
  __bf16* xb    = wsb;  wsb += (size_t)M * DI;               // 50.3 MB
  __bf16* zbuf  = wsb;  wsb += (size_t)M * DI;               // 50.3 MB
  __bf16* xcb   = wsb;  wsb += (size_t)M * DI;               // 50.3 MB
  __bf16* dltb  = wsb;  wsb += (size_t)M * DI;               // 50.3 MB (bf16 delta)
  __bf16* xdblb = wsb;  wsb += (size_t)M * 80;               // 2.6 MB
  __bf16* ebw   = wsb;  wsb += (size_t)VOCP * DM;            // 3.1 MB
  __bf16* inwb  = wsb;  wsb += (size_t)4 * 2 * DI * DM;      // 18.9 MB
  __bf16* xwb   = wsb;  wsb += (size_t)4 * 128 * DI;         // 1.6 MB
  __bf16* owb   = wsb;  wsb += (size_t)4 * DM * DI;          // 9.4 MB
  __bf16* dtwb  = wsb;  wsb += (size_t)4 * DI * 64;          // 0.8 MB

  // weight / embed conversions (every call; deterministic)
  k_f2b<<<2048, 256, 0, stream>>>(inw, inwb, (4 * 2 * DI * DM) / 4);
  k_f2b<<<2048, 256, 0, stream>>>(ow,  owb,  (4 * DM * DI) / 4);
  k_f2b_pad<<<2048, 256, 0, stream>>>(emb, ebw, 1, VOC, VOCP, DM, DM);
  k_f2b_pad<<<1024, 256, 0, stream>>>(xw,  xwb, 4, 80, 128, DI, DI);
  k_f2b_pad<<<1024, 256, 0, stream>>>(dtw, dtwb, 4, DI, DI, DR, 64);

  k_embed<<<M, 256, 0, stream>>>(ids, times, emb, tw, tb, h);

  for (int i = 0; i < 4; i++) {
    k_rmsnorm<<<M, 256, 0, stream>>>(h, nw + i * DM, hnb);
    {  // x = hn @ in_proj_x^T ; z = hn @ in_proj_z^T   (bf16 out, pipelined GEMM)
      dim3 g(M / 256, DI / 128);
      k_gemm_big<<<g, 512, 0, stream>>>(hnb, DM, inwb + (size_t)i * 2 * DI * DM, DM,
                                        nullptr, nullptr, xb, DI, DI, DM, 0, 0);
      k_gemm_big<<<g, 512, 0, stream>>>(hnb, DM,
                                        inwb + (size_t)i * 2 * DI * DM + (size_t)DI * DM, DM,
                                        nullptr, nullptr, zbuf, DI, DI, DM, 0, 0);
    }
    {  // xcb = silu(conv1d(x) + cb)
      int blocks = (int)(((size_t)M * DI / 8) / 256);
      k_conv8<<<blocks, 256, 0, stream>>>(xb, cw + i * DI * DC, cb + i * DI, xcb);
    }
    {  // xdbl = xc @ x_proj^T  (bf16 out, N=80, padded weights; small kernel)
      dim3 g(M / 128, 1);
      k_gemm_mfma<<<g, 256, 0, stream>>>(xcb, DI, xwb + (size_t)i * 128 * DI, DI,
                                         nullptr, nullptr, xdblb, 80, 80, DI, 0, 0);
    }
    {  // delta = softplus(xdbl @ dtw_pad^T + dtb)  -> bf16 (K=64; small kernel)
      dim3 g(M / 128, DI / 128);
      k_gemm_mfma<<<g, 256, 0, stream>>>(xdblb, 80, dtwb + (size_t)i * DI * 64, 64,
                                         dtb + i * DI, nullptr, dltb, DI, DI, 64, 1, 0);
    }
    {  // chunked selective scan + y*silu(z), in place over xcb
      dim3 g1(DI / 256, NC, Bc);
      k_scan1<<<g1, 256, 0, stream>>>(dltb, xcb, xdblb, alog + (size_t)i * DI * DS, scb);
      k_scan2<<<(Bc * DI * DS) / 256, 256, 0, stream>>>(scb);
      k_scan3<<<g1, 256, 0, stream>>>(dltb, zbuf, xcb, xdblb,
                                      alog + (size_t)i * DI * DS, dsk + i * DI, scb);
    }
    {  // h += y @ out_proj^T   (f32, resAdd, pipelined GEMM)
      dim3 g(M / 256, DM / 128);
      k_gemm_big<<<g, 512, 0, stream>>>(xcb, DI, owb + (size_t)i * DM * DI, DI,
                                        nullptr, h, nullptr, DM, DM, DI, 0, 1);
    }
  }

  k_rmsnorm<<<M, 256, 0, stream>>>(h, nfw, hnb);
  {  // logits = hn @ embed^T   (N=1969, padded rows, pipelined GEMM)
    dim3 g(M / 256, VOCP / 128);
    k_gemm_big<<<g, 512, 0, stream>>>(hnb, DM, ebw, DM,
                                      nullptr, out, nullptr, VOC, VOC, DM, 0, 0);
  }
}

// Round 8
// 2899.721 us; speedup vs baseline: 1.0138x; 1.0138x over previous
//
#include <hip/hip_runtime.h>
#include <hip/hip_bf16.h>
#include <math.h>

namespace {

constexpr int Bc  = 8;
constexpr int Lc  = 2048;
constexpr int VOC = 1969;
constexpr int VOCP = 2048;            // padded vocab rows for logits GEMM
constexpr int DM  = 768;
constexpr int DI  = 1536;
constexpr int DS  = 16;
constexpr int DC  = 4;
constexpr int DR  = 48;
constexpr int M   = Bc * Lc;          // 16384 rows
constexpr int NC  = 32;               // scan chunks
constexpr int CT  = Lc / NC;          // 64 timesteps per chunk
constexpr float EPS_ = 1e-5f;

typedef __bf16 bf16x8 __attribute__((ext_vector_type(8)));
typedef float  f32x4  __attribute__((ext_vector_type(4)));

__device__ __forceinline__ float siluf(float x) { return x / (1.f + __expf(-x)); }
__device__ __forceinline__ float softplusf(float x) {
  return (x > 20.f) ? x : __logf(1.f + __expf(x));
}

#define GLOAD16(gp, lp)                                                        \
  __builtin_amdgcn_global_load_lds(                                            \
      (const __attribute__((address_space(1))) void*)(gp),                     \
      (__attribute__((address_space(3))) void*)(lp), 16, 0, 0)

// -------- f32 -> bf16 conversion (packed) --------
__global__ __launch_bounds__(256) void k_f2b(const float* __restrict__ in,
                                             __bf16* __restrict__ out, int n4) {
  for (int i = blockIdx.x * 256 + threadIdx.x; i < n4; i += gridDim.x * 256) {
    float4 v = *(const float4*)(in + (size_t)i * 4);
    __bf16* o = out + (size_t)i * 4;
    o[0] = (__bf16)v.x; o[1] = (__bf16)v.y; o[2] = (__bf16)v.z; o[3] = (__bf16)v.w;
  }
}

// f32 -> bf16 with per-layer row/col zero-padding.
__global__ __launch_bounds__(256) void k_f2b_pad(const float* __restrict__ in,
                                                 __bf16* __restrict__ out,
                                                 int layers, int rin, int rout,
                                                 int cin, int cout) {
  size_t total = (size_t)layers * rout * cout;
  for (size_t i = (size_t)blockIdx.x * 256 + threadIdx.x; i < total;
       i += (size_t)gridDim.x * 256) {
    int lay = (int)(i / ((size_t)rout * cout));
    int rem = (int)(i % ((size_t)rout * cout));
    int r = rem / cout, c = rem % cout;
    float v = (r < rin && c < cin) ? in[((size_t)lay * rin + r) * cin + c] : 0.f;
    out[i] = (__bf16)v;
  }
}

// h[row,d] = embed[ids[row]][d] + times[row]*time_w[d] + time_b[d]
__global__ void k_embed(const int* __restrict__ ids, const float* __restrict__ times,
                        const float* __restrict__ emb, const float* __restrict__ tw,
                        const float* __restrict__ tb, float* __restrict__ h) {
  int row = blockIdx.x;
  int id  = ids[row];
  float tv = times[row];
  const float* e = emb + (size_t)id * DM;
  for (int d = threadIdx.x; d < DM; d += blockDim.x)
    h[(size_t)row * DM + d] = e[d] + tv * tw[d] + tb[d];
}

// bf16 out: o[row,:] = x[row,:] * rsqrt(mean(x^2)+eps) * w
__global__ __launch_bounds__(256) void k_rmsnorm(const float* __restrict__ x,
                                                 const float* __restrict__ w,
                                                 __bf16* __restrict__ o) {
  int row = blockIdx.x;
  const float* xr = x + (size_t)row * DM;
  float v[3];
  float s = 0.f;
#pragma unroll
  for (int i = 0; i < 3; i++) { v[i] = xr[threadIdx.x + 256 * i]; s += v[i] * v[i]; }
#pragma unroll
  for (int off = 32; off > 0; off >>= 1) s += __shfl_down(s, off);
  __shared__ float red[4];
  int lane = threadIdx.x & 63, wv = threadIdx.x >> 6;
  if (lane == 0) red[wv] = s;
  __syncthreads();
  if (threadIdx.x == 0)
    red[0] = rsqrtf((red[0] + red[1] + red[2] + red[3]) / (float)DM + EPS_);
  __syncthreads();
  float sc = red[0];
#pragma unroll
  for (int i = 0; i < 3; i++) {
    int d = threadIdx.x + 256 * i;
    o[(size_t)row * DM + d] = (__bf16)(v[i] * sc * w[d]);
  }
}

// Depthwise causal conv (width 4) + bias + silu ; bf16x8 vectorized.
// x lives in xz buffer: row stride 2*DI, x at cols [0, DI). Output dense [M][DI].
__global__ __launch_bounds__(256) void k_conv8(const __bf16* __restrict__ xzb,
                                               const float* __restrict__ cwt,
                                               const float* __restrict__ cbv,
                                               __bf16* __restrict__ xo) {
  size_t idx = (size_t)blockIdx.x * 256 + threadIdx.x;   // < M*DI/8
  int dg = (int)(idx % (DI / 8));
  size_t row = idx / (DI / 8);
  int d0 = dg * 8;
  int t = (int)(row % Lc);
  size_t b = row / Lc;
  float acc[8];
  float4 cwv[8];
#pragma unroll
  for (int j = 0; j < 8; j++) {
    acc[j] = cbv[d0 + j];
    cwv[j] = *(const float4*)(cwt + (d0 + j) * DC);
  }
#pragma unroll
  for (int tap = 0; tap < DC; tap++) {
    int tt = t - (DC - 1) + tap;
    if (tt >= 0) {
      bf16x8 v = *(const bf16x8*)(xzb + ((size_t)b * Lc + tt) * (2 * DI) + d0);
#pragma unroll
      for (int j = 0; j < 8; j++) {
        float wt = (tap == 0) ? cwv[j].x : (tap == 1) ? cwv[j].y
                   : (tap == 2) ? cwv[j].z : cwv[j].w;
        acc[j] += wt * (float)v[j];
      }
    }
  }
  bf16x8 o;
#pragma unroll
  for (int j = 0; j < 8; j++) o[j] = (__bf16)siluf(acc[j]);
  *(bf16x8*)(xo + idx * 8) = o;
}

// ==== pipelined bf16 MFMA GEMM: 128x128 tile, BK=32, 4 LDS buffers, counted vmcnt ====
// C[M x N] (+)= act(A[M x K(lda)] * W[N x K(ldw)]^T + bias)
// 256 threads = 4 waves (2x2), 64x64 per wave. LDS 4 x 16KB = 64KB -> 2 blocks/CU.
// Depth-3 prefetch; per-wave 4 global_load_lds per tile; steady-state vmcnt(12),
// tail 8/4/0; raw s_barrier (no full drain). Swizzle: slot rot f(r)=r+(r>>2), both-sides.
__global__ __launch_bounds__(256, 2) void k_gemm_p(
    const __bf16* __restrict__ A, int lda,
    const __bf16* __restrict__ W, int ldw,
    const float* __restrict__ bias,
    float* __restrict__ Cf, __bf16* __restrict__ Cb, int ldc,
    int N, int K, int act, int resAdd) {
  constexpr int BUFE = 8192;            // elements per buffer: A 4096 + B 4096
  __shared__ __bf16 lds[4 * BUFE];      // 64 KB
  int tid = threadIdx.x;
  int l = tid & 63, w = tid >> 6;
  int wr = w >> 1, wc = w & 1;
  int bm = blockIdx.x << 7, bn = blockIdx.y << 7;

  // staging: wave w stages rows [32w, 32w+32) of A and B; lane l -> row r, slot l&3
  int r0 = w * 32 + (l >> 2);
  int r1 = r0 + 16;
  int sg0 = ((l & 3) - r0 - (r0 >> 2)) & 3;     // pre-permuted global k-slot
  int sg1 = ((l & 3) - r1 - (r1 >> 2)) & 3;
  const char* gA0 = (const char*)(A + (size_t)(bm + r0) * lda) + sg0 * 16;
  const char* gA1 = (const char*)(A + (size_t)(bm + r1) * lda) + sg1 * 16;
  const char* gB0 = (const char*)(W + (size_t)(bn + r0) * ldw) + sg0 * 16;
  const char* gB1 = (const char*)(W + (size_t)(bn + r1) * ldw) + sg1 * 16;
  int lA0 = (w * 32) * 32;                      // wave-uniform LDS bases (elements)
  int lA1 = (w * 32 + 16) * 32;
  int lB0 = 4096 + (w * 32) * 32;
  int lB1 = 4096 + (w * 32 + 16) * 32;

  // fragment read offsets (elements), constant across K
  int aoff[4], boff[4];
#pragma unroll
  for (int i = 0; i < 4; i++) {
    int ra = wr * 64 + i * 16 + (l & 15);
    aoff[i] = ra * 32 + ((((l >> 4) + ra + (ra >> 2)) & 3) << 3);
    int rb = wc * 64 + i * 16 + (l & 15);
    boff[i] = 4096 + rb * 32 + ((((l >> 4) + rb + (rb >> 2)) & 3) << 3);
  }

  f32x4 acc[4][4];
#pragma unroll
  for (int i = 0; i < 4; i++)
#pragma unroll
    for (int j = 0; j < 4; j++)
#pragma unroll
      for (int e = 0; e < 4; e++) acc[i][j][e] = 0.f;

#define ISSUE(t)                                                               \
  do {                                                                         \
    __bf16* Lb_ = lds + ((t) & 3) * BUFE;                                      \
    size_t kb_ = (size_t)(t) * 64;                                             \
    GLOAD16(gA0 + kb_, Lb_ + lA0);                                             \
    GLOAD16(gA1 + kb_, Lb_ + lA1);                                             \
    GLOAD16(gB0 + kb_, Lb_ + lB0);                                             \
    GLOAD16(gB1 + kb_, Lb_ + lB1);                                             \
  } while (0)

  int NT = K >> 5;
  if (NT > 0) ISSUE(0);
  if (NT > 1) ISSUE(1);
  if (NT > 2) ISSUE(2);

  for (int t = 0; t < NT; ++t) {
    __builtin_amdgcn_s_barrier();               // all waves done with buf[(t+3)&3]
    __builtin_amdgcn_sched_barrier(0);
    if (t + 3 < NT) ISSUE(t + 3);
    int rem = NT - t;
    if (rem >= 4)      asm volatile("s_waitcnt vmcnt(12)" ::: "memory");
    else if (rem == 3) asm volatile("s_waitcnt vmcnt(8)" ::: "memory");
    else if (rem == 2) asm volatile("s_waitcnt vmcnt(4)" ::: "memory");
    else               asm volatile("s_waitcnt vmcnt(0)" ::: "memory");
    __builtin_amdgcn_s_barrier();               // every wave's tile-t loads landed
    __builtin_amdgcn_sched_barrier(0);

    const __bf16* Lb = lds + (t & 3) * BUFE;
    bf16x8 af[4], bfr[4];
#pragma unroll
    for (int i = 0; i < 4; i++) {
      af[i]  = *(const bf16x8*)(Lb + aoff[i]);
      bfr[i] = *(const bf16x8*)(Lb + boff[i]);
    }
    __builtin_amdgcn_s_setprio(1);
#pragma unroll
    for (int i = 0; i < 4; i++)
#pragma unroll
      for (int j = 0; j < 4; j++)
        acc[i][j] = __builtin_amdgcn_mfma_f32_16x16x32_bf16(af[i], bfr[j], acc[i][j], 0, 0, 0);
    __builtin_amdgcn_s_setprio(0);
  }
#undef ISSUE

#pragma unroll
  for (int i = 0; i < 4; i++) {
#pragma unroll
    for (int r = 0; r < 4; r++) {
      int grow = bm + wr * 64 + i * 16 + (l >> 4) * 4 + r;
#pragma unroll
      for (int j = 0; j < 4; j++) {
        int gcol = bn + wc * 64 + j * 16 + (l & 15);
        if (gcol < N) {
          float v = acc[i][j][r];
          if (bias) v += bias[gcol];
          if (act == 1) v = softplusf(v);
          size_t off = (size_t)grow * ldc + gcol;
          if (Cb) Cb[off] = (__bf16)v;
          else if (resAdd) Cf[off] += v;
          else Cf[off] = v;
        }
      }
    }
  }
}

// ---------------- chunked selective scan ----------------
// delta: bf16 [M][DI]; u: bf16 [M][DI]; B/C: bf16 xdbl [M][80]; z in xz buffer.
__global__ __launch_bounds__(256) void k_scan1(
    const __bf16* __restrict__ dlt,
    const __bf16* __restrict__ u_xc,
    const __bf16* __restrict__ xdbl,
    const float* __restrict__ alog,
    float* __restrict__ sc) {
  __shared__ float bcs[CT][32];
  int b = blockIdx.z, c = blockIdx.y;
  int d = blockIdx.x * 256 + threadIdx.x;
  int row0 = b * Lc + c * CT;
#pragma unroll
  for (int k = 0; k < (CT * 32) / 256; k++) {
    int i = k * 256 + threadIdx.x;
    int t = i >> 5, j = i & 31;
    bcs[t][j] = (float)xdbl[(size_t)(row0 + t) * 80 + 48 + j];
  }
  float Av[16];
#pragma unroll
  for (int n = 0; n < 16; n++) Av[n] = -__expf(alog[d * DS + n]);
  float h[16], P[16];
#pragma unroll
  for (int n = 0; n < 16; n++) { h[n] = 0.f; P[n] = 1.f; }
  __syncthreads();
  for (int t = 0; t < CT; t++) {
    size_t row = row0 + t;
    float dl = (float)dlt[row * DI + d];
    float u  = (float)u_xc[row * DI + d];
    float du = dl * u;
#pragma unroll
    for (int n = 0; n < 16; n++) {
      float e = __expf(dl * Av[n]);
      h[n] = h[n] * e + du * bcs[t][n];
      P[n] *= e;
    }
  }
  float* o = sc + (((size_t)b * NC + c) * DI + d) * 32;
#pragma unroll
  for (int n = 0; n < 16; n += 4) {
    *(float4*)(o + n)      = make_float4(h[n], h[n + 1], h[n + 2], h[n + 3]);
    *(float4*)(o + 16 + n) = make_float4(P[n], P[n + 1], P[n + 2], P[n + 3]);
  }
}

__global__ __launch_bounds__(256) void k_scan2(float* __restrict__ sc) {
  int g = blockIdx.x * 256 + threadIdx.x;
  int n = g & 15;
  int rest = g >> 4;
  int d = rest % DI;
  int b = rest / DI;
  float cur = 0.f;
  for (int c = 0; c < NC; c++) {
    float* p = sc + (((size_t)b * NC + c) * DI + d) * 32;
    float hf = p[n];
    float pd = p[16 + n];
    p[n] = cur;
    cur = pd * cur + hf;
  }
}

__global__ __launch_bounds__(256) void k_scan3(
    const __bf16* __restrict__ dlt,
    const __bf16* __restrict__ xzb,     // z at [row*2*DI + DI + d]
    __bf16* __restrict__ u_xc,          // in: u, out: y*silu(z)
    const __bf16* __restrict__ xdbl,
    const float* __restrict__ alog,
    const float* __restrict__ dsk,
    const float* __restrict__ sc) {
  __shared__ float bcs[CT][32];
  int b = blockIdx.z, c = blockIdx.y;
  int d = blockIdx.x * 256 + threadIdx.x;
  int row0 = b * Lc + c * CT;
#pragma unroll
  for (int k = 0; k < (CT * 32) / 256; k++) {
    int i = k * 256 + threadIdx.x;
    int t = i >> 5, j = i & 31;
    bcs[t][j] = (float)xdbl[(size_t)(row0 + t) * 80 + 48 + j];
  }
  float Av[16];
#pragma unroll
  for (int n = 0; n < 16; n++) Av[n] = -__expf(alog[d * DS + n]);
  float Dv = dsk[d];
  float h[16];
  const float* ip = sc + (((size_t)b * NC + c) * DI + d) * 32;
#pragma unroll
  for (int n = 0; n < 16; n += 4) {
    float4 v = *(const float4*)(ip + n);
    h[n] = v.x; h[n + 1] = v.y; h[n + 2] = v.z; h[n + 3] = v.w;
  }
  __syncthreads();
  for (int t = 0; t < CT; t++) {
    size_t row = row0 + t;
    float dl = (float)dlt[row * DI + d];
    float u  = (float)u_xc[row * DI + d];
    float du = dl * u;
    float y = 0.f;
#pragma unroll
    for (int n = 0; n < 16; n++) {
      float e = __expf(dl * Av[n]);
      h[n] = h[n] * e + du * bcs[t][n];
      y += h[n] * bcs[t][16 + n];
    }
    y += u * Dv;
    float z = (float)xzb[row * (2 * DI) + DI + d];
    u_xc[row * DI + d] = (__bf16)(y * siluf(z));
  }
}

}  // namespace

extern "C" void kernel_launch(void* const* d_in, const int* in_sizes, int n_in,
                              void* d_out, int out_size, void* d_ws, size_t ws_size,
                              hipStream_t stream) {
  const int*   ids   = (const int*)d_in[0];
  const float* times = (const float*)d_in[1];
  const float* emb   = (const float*)d_in[3];
  const float* tw    = (const float*)d_in[4];
  const float* tb    = (const float*)d_in[5];
  const float* inw   = (const float*)d_in[6];
  const float* cw    = (const float*)d_in[7];
  const float* cb    = (const float*)d_in[8];
  const float* xw    = (const float*)d_in[9];
  const float* dtw   = (const float*)d_in[10];
  const float* dtb   = (const float*)d_in[11];
  const float* alog  = (const float*)d_in[12];
  const float* dsk   = (const float*)d_in[13];
  const float* ow    = (const float*)d_in[14];
  const float* nw    = (const float*)d_in[15];
  const float* nfw   = (const float*)d_in[16];
  float* out = (float*)d_out;

  // ---- workspace layout (f32 first, then bf16; all 16B aligned) ----
  float* wsf  = (float*)d_ws;
  float* h    = wsf;  wsf += (size_t)M * DM;                 // 50.3 MB
  float* scb  = wsf;  wsf += (size_t)Bc * NC * DI * 32;      // 50.3 MB
  __bf16* wsb = (__bf16*)wsf;
  __bf16* hnb   = wsb;  wsb += (size_t)M * DM;               // 25.2 MB
  __bf16* xzb   = wsb;  wsb += (size_t)M * (2 * DI);         // 100.7 MB (x | z)
  __bf16* xcb   = wsb;  wsb += (size_t)M * DI;               // 50.3 MB (u, then y)
  __bf16* dltb  = wsb;  wsb += (size_t)M * DI;               // 50.3 MB
  __bf16* xdblb = wsb;  wsb += (size_t)M * 80;               // 2.6 MB
  __bf16* ebw   = wsb;  wsb += (size_t)VOCP * DM;            // 3.1 MB
  __bf16* inwb  = wsb;  wsb += (size_t)4 * 2 * DI * DM;      // 18.9 MB
  __bf16* xwb   = wsb;  wsb += (size_t)4 * 128 * DI;         // 1.6 MB
  __bf16* owb   = wsb;  wsb += (size_t)4 * DM * DI;          // 9.4 MB
  __bf16* dtwb  = wsb;  wsb += (size_t)4 * DI * 64;          // 0.8 MB

  // weight / embed conversions (every call; deterministic)
  k_f2b<<<2048, 256, 0, stream>>>(inw, inwb, (4 * 2 * DI * DM) / 4);
  k_f2b<<<2048, 256, 0, stream>>>(ow,  owb,  (4 * DM * DI) / 4);
  k_f2b_pad<<<2048, 256, 0, stream>>>(emb, ebw, 1, VOC, VOCP, DM, DM);
  k_f2b_pad<<<1024, 256, 0, stream>>>(xw,  xwb, 4, 80, 128, DI, DI);
  k_f2b_pad<<<1024, 256, 0, stream>>>(dtw, dtwb, 4, DI, DI, DR, 64);

  k_embed<<<M, 256, 0, stream>>>(ids, times, emb, tw, tb, h);

  for (int i = 0; i < 4; i++) {
    k_rmsnorm<<<M, 256, 0, stream>>>(h, nw + i * DM, hnb);
    {  // xz = hn @ in_proj^T  (single N=3072 dispatch, bf16 out)
      dim3 g(M / 128, (2 * DI) / 128);
      k_gemm_p<<<g, 256, 0, stream>>>(hnb, DM, inwb + (size_t)i * 2 * DI * DM, DM,
                                      nullptr, nullptr, xzb, 2 * DI, 2 * DI, DM, 0, 0);
    }
    {  // xcb = silu(conv1d(x) + cb)
      int blocks = (int)(((size_t)M * DI / 8) / 256);
      k_conv8<<<blocks, 256, 0, stream>>>(xzb, cw + i * DI * DC, cb + i * DI, xcb);
    }
    {  // xdbl = xc @ x_proj^T  (bf16 out, N=80, padded weights)
      dim3 g(M / 128, 1);
      k_gemm_p<<<g, 256, 0, stream>>>(xcb, DI, xwb + (size_t)i * 128 * DI, DI,
                                      nullptr, nullptr, xdblb, 80, 80, DI, 0, 0);
    }
    {  // delta = softplus(xdbl @ dtw_pad^T + dtb)  -> bf16 (K=64)
      dim3 g(M / 128, DI / 128);
      k_gemm_p<<<g, 256, 0, stream>>>(xdblb, 80, dtwb + (size_t)i * DI * 64, 64,
                                      dtb + i * DI, nullptr, dltb, DI, DI, 64, 1, 0);
    }
    {  // chunked selective scan + y*silu(z), in place over xcb
      dim3 g1(DI / 256, NC, Bc);
      k_scan1<<<g1, 256, 0, stream>>>(dltb, xcb, xdblb, alog + (size_t)i * DI * DS, scb);
      k_scan2<<<(Bc * DI * DS) / 256, 256, 0, stream>>>(scb);
      k_scan3<<<g1, 256, 0, stream>>>(dltb, xzb, xcb, xdblb,
                                      alog + (size_t)i * DI * DS, dsk + i * DI, scb);
    }
    {  // h += y @ out_proj^T   (f32, resAdd)
      dim3 g(M / 128, DM / 128);
      k_gemm_p<<<g, 256, 0, stream>>>(xcb, DI, owb + (size_t)i * DM * DI, DI,
                                      nullptr, h, nullptr, DM, DM, DI, 0, 1);
    }
  }

  k_rmsnorm<<<M, 256, 0, stream>>>(h, nfw, hnb);
  {  // logits = hn @ embed^T   (N=1969, padded rows)
    dim3 g(M / 128, VOCP / 128);
    k_gemm_p<<<g, 256, 0, stream>>>(hnb, DM, ebw, DM,
                                    nullptr, out, nullptr, VOC, VOC, DM, 0, 0);
  }
}